// Round 1
// baseline (228.981 us; speedup 1.0000x reference)
//
#include <hip/hip_runtime.h>

// Output: 4 tensors of shape (32, 20, 14, 14, 14, 14) fp32, concatenated.
// S_PER = 32*20*14^4 elements per tensor.
#define S_PER 24586240u
#define NTENSOR_STRIDE (51 * 196)   // one of corner1/corner2/center1/center2
#define N_STRIDE (204 * 196)        // per-batch stride in input

__global__ __launch_bounds__(256) void plnet_kernel(const float* __restrict__ in,
                                                    float* __restrict__ out) {
    const unsigned tid = blockIdx.x * 256u + threadIdx.x;
    const unsigned base = tid * 4u;   // first of 4 consecutive flat elements

    float v1[4], v2[4], v3[4], v4[4];

#pragma unroll
    for (int j = 0; j < 4; ++j) {
        unsigned i = base + (unsigned)j;
        unsigned d5 = i % 14u; unsigned t = i / 14u;
        unsigned d4 = t % 14u; t /= 14u;
        unsigned d3 = t % 14u; t /= 14u;
        unsigned d2 = t % 14u; t /= 14u;
        unsigned q  = t % 20u; unsigned n = t / 20u;

        const float* g    = in + (size_t)n * N_STRIDE;
        const float* cor1 = g;
        const float* cor2 = g + NTENSOR_STRIDE;
        const float* cen1 = g + 2 * NTENSOR_STRIDE;
        const float* cen2 = g + 3 * NTENSOR_STRIDE;

        const unsigned pc = d2 * 14u + d3;   // corner spatial offset (h=d2, w=d3)
        const unsigned ps = d4 * 14u + d5;   // center spatial offset (h=d4, w=d5)

        // A factors (corner): cor[0]*cor[1+q] at (d2,d3)
        float a1 = cor1[pc] * cor1[(1u + q) * 196u + pc];
        float a2 = cor2[pc] * cor2[(1u + q) * 196u + pc];
        // Lcx/Lcy (corner): channels 23+d4 / 37+d5 at (d2,d3)
        float cx1 = cor1[(23u + d4) * 196u + pc];
        float cy1 = cor1[(37u + d5) * 196u + pc];
        float cx2 = cor2[(23u + d4) * 196u + pc];
        float cy2 = cor2[(37u + d5) * 196u + pc];
        // B factors (center): cen[0]*cen[1+q] at (d4,d5)
        float b1 = cen1[ps] * cen1[(1u + q) * 196u + ps];
        float b2 = cen2[ps] * cen2[(1u + q) * 196u + ps];
        // Lsx/Lsy (center): channels 23+d2 / 37+d3 at (d4,d5)
        float sx1 = cen1[(23u + d2) * 196u + ps];
        float sy1 = cen1[(37u + d3) * 196u + ps];
        float sx2 = cen2[(23u + d2) * 196u + ps];
        float sy2 = cen2[(37u + d3) * 196u + ps];

        float c1 = 0.5f * a1 * cx1 * cy1;   // corner1 group
        float c2 = 0.5f * a2 * cx2 * cy2;   // corner2 group
        float e1 = b1 * sx1 * sy1;          // center1 group
        float e2 = b2 * sx2 * sy2;          // center2 group

        v1[j] = c1 * e1;   // p1 = (corner1, center1)
        v2[j] = c2 * e1;   // p2 = (corner2, center1)
        v3[j] = c1 * e2;   // p3 = (corner1, center2)
        v4[j] = c2 * e2;   // p4 = (corner2, center2)
    }

    float4* o = (float4*)out;
    const unsigned f4 = tid;               // float4 index within p1 region
    const unsigned sp4 = S_PER / 4u;       // float4 stride between output tensors
    o[f4]            = make_float4(v1[0], v1[1], v1[2], v1[3]);
    o[f4 + sp4]      = make_float4(v2[0], v2[1], v2[2], v2[3]);
    o[f4 + 2u * sp4] = make_float4(v3[0], v3[1], v3[2], v3[3]);
    o[f4 + 3u * sp4] = make_float4(v4[0], v4[1], v4[2], v4[3]);
}

extern "C" void kernel_launch(void* const* d_in, const int* in_sizes, int n_in,
                              void* d_out, int out_size, void* d_ws, size_t ws_size,
                              hipStream_t stream) {
    const float* in = (const float*)d_in[0];
    float* out = (float*)d_out;
    // total float4 stores per tensor: S_PER/4 = 6,146,560 = 24010 * 256 exactly
    const unsigned nthreads_total = S_PER / 4u;
    dim3 grid(nthreads_total / 256u);
    dim3 block(256);
    plnet_kernel<<<grid, block, 0, stream>>>(in, out);
}

// Round 2
// 121.818 us; speedup vs baseline: 1.8797x; 1.8797x over previous
//
#include <hip/hip_runtime.h>

// out: 4 tensors (32, 20, 14, 14, 14, 14) fp32 concatenated.
// Decomposition per block (fixed n, pc=(d2,d3)):
//   out_p[q][ps] = K_i(q) * M_ij[ps] * cen_j[1+q][ps]
//   K_i(q)  = 0.5 * cor_i[0][pc] * cor_i[1+q][pc]
//   M_ij[ps]= Lcx_i[d4]*Lcy_i[d5] * E_j[ps]
//   E_j[ps] = cen_j[0][ps] * cen_j[23+d2][ps] * cen_j[37+d3][ps]
// p1=(i=1,j=1) p2=(2,1) p3=(1,2) p4=(2,2)

#define S_PER 24586240u            // 32*20*14^4
#define TSTRIDE (51 * 196)
#define N_STRIDE (204 * 196)

__global__ __launch_bounds__(256) void plnet_kernel(const float* __restrict__ in,
                                                    float* __restrict__ out) {
    __shared__ float sK1[20], sK2[20];
    __shared__ float sLcx1[14], sLcy1[14], sLcx2[14], sLcy2[14];
    __shared__ float sM11[196], sM21[196], sM12[196], sM22[196];

    const unsigned b  = blockIdx.x;
    const unsigned n  = b / 196u;
    const unsigned pc = b % 196u;
    const unsigned d2 = pc / 14u;
    const unsigned d3 = pc % 14u;

    const float* g    = in + (size_t)n * N_STRIDE;
    const float* cor1 = g;
    const float* cor2 = g + TSTRIDE;
    const float* cen1 = g + 2 * TSTRIDE;
    const float* cen2 = g + 3 * TSTRIDE;

    const unsigned tid = threadIdx.x;

    // Phase A: 196 threads load the center factor product E_j[ps] (registers);
    // 60 threads load the 96 small corner-side scalars into LDS.
    float e1 = 0.f, e2 = 0.f;
    if (tid < 196u) {
        const unsigned ps = tid;
        e1 = cen1[ps] * cen1[(23u + d2) * 196u + ps] * cen1[(37u + d3) * 196u + ps];
        e2 = cen2[ps] * cen2[(23u + d2) * 196u + ps] * cen2[(37u + d3) * 196u + ps];
    } else {
        unsigned s = tid - 196u;                 // 0..59
        for (unsigned item = s; item < 96u; item += 60u) {
            if (item < 20u)      sK1[item]        = 0.5f * cor1[pc] * cor1[(1u + item) * 196u + pc];
            else if (item < 40u) sK2[item - 20u]  = 0.5f * cor2[pc] * cor2[(item - 19u) * 196u + pc];
            else if (item < 54u) sLcx1[item - 40u] = cor1[(item - 17u) * 196u + pc];  // 23 + (item-40)
            else if (item < 68u) sLcy1[item - 54u] = cor1[(item - 17u) * 196u + pc];  // 37 + (item-54)
            else if (item < 82u) sLcx2[item - 68u] = cor2[(item - 45u) * 196u + pc];  // 23 + (item-68)
            else                 sLcy2[item - 82u] = cor2[(item - 45u) * 196u + pc];  // 37 + (item-82)
        }
    }
    __syncthreads();

    // Phase B: build the four M tables.
    if (tid < 196u) {
        const unsigned d4 = tid / 14u, d5 = tid % 14u;
        const float f1 = sLcx1[d4] * sLcy1[d5];
        const float f2 = sLcx2[d4] * sLcy2[d5];
        sM11[tid] = f1 * e1;
        sM21[tid] = f2 * e1;
        sM12[tid] = f1 * e2;
        sM22[tid] = f2 * e2;
    }
    __syncthreads();

    // Main loop: 20 q * 49 float4-chunks = 980 work items.
    for (unsigned c = tid; c < 980u; c += 256u) {
        const unsigned q = c / 49u;
        const unsigned f = c - q * 49u;
        const unsigned e = 4u * f;               // element offset within ps row

        const float4 x1 = *(const float4*)&cen1[(1u + q) * 196u + e];
        const float4 x2 = *(const float4*)&cen2[(1u + q) * 196u + e];
        const float4 m11 = *(const float4*)&sM11[e];
        const float4 m21 = *(const float4*)&sM21[e];
        const float4 m12 = *(const float4*)&sM12[e];
        const float4 m22 = *(const float4*)&sM22[e];
        const float k1 = sK1[q], k2 = sK2[q];

        const size_t base = ((size_t)(n * 20u + q) * 196u + pc) * 196u + e;
        float4* o1 = (float4*)(out + base);
        float4* o2 = (float4*)(out + (size_t)S_PER + base);
        float4* o3 = (float4*)(out + 2u * (size_t)S_PER + base);
        float4* o4 = (float4*)(out + 3u * (size_t)S_PER + base);

        *o1 = make_float4(k1 * m11.x * x1.x, k1 * m11.y * x1.y,
                          k1 * m11.z * x1.z, k1 * m11.w * x1.w);
        *o2 = make_float4(k2 * m21.x * x1.x, k2 * m21.y * x1.y,
                          k2 * m21.z * x1.z, k2 * m21.w * x1.w);
        *o3 = make_float4(k1 * m12.x * x2.x, k1 * m12.y * x2.y,
                          k1 * m12.z * x2.z, k1 * m12.w * x2.w);
        *o4 = make_float4(k2 * m22.x * x2.x, k2 * m22.y * x2.y,
                          k2 * m22.z * x2.z, k2 * m22.w * x2.w);
    }
}

extern "C" void kernel_launch(void* const* d_in, const int* in_sizes, int n_in,
                              void* d_out, int out_size, void* d_ws, size_t ws_size,
                              hipStream_t stream) {
    const float* in = (const float*)d_in[0];
    float* out = (float*)d_out;
    dim3 grid(32 * 196);           // one block per (n, d2, d3)
    dim3 block(256);
    plnet_kernel<<<grid, block, 0, stream>>>(in, out);
}

// Round 3
// 106.486 us; speedup vs baseline: 2.1503x; 1.1440x over previous
//
#include <hip/hip_runtime.h>

// out: 4 tensors (32, 20, 14, 14, 14, 14) fp32 concatenated.
// Per block (fixed n, pc=(d2,d3)):
//   out_p[q][ps] = K_i(q) * M_ij[ps] * cen_j[1+q][ps]
//   K_i(q)  = 0.5 * cor_i[0][pc] * cor_i[1+q][pc]
//   M_ij[ps]= Lcx_i[d4]*Lcy_i[d5] * E_j[ps]
//   E_j[ps] = cen_j[0][ps] * cen_j[23+d2][ps] * cen_j[37+d3][ps]
// p1=(i1,j1) p2=(i2,j1) p3=(i1,j2) p4=(i2,j2)

#define S_PER 24586240u            // 32*20*14^4
#define TSTRIDE (51 * 196)
#define N_STRIDE (204 * 196)
#define QSTEP (5u * 196u * 196u)   // element stride between q and q+5 in one tensor

__global__ __launch_bounds__(256) void plnet_kernel(const float* __restrict__ in,
                                                    float* __restrict__ out) {
    __shared__ float sK1[20], sK2[20];
    __shared__ float sM11[196], sM21[196], sM12[196], sM22[196];

    const unsigned b  = blockIdx.x;
    const unsigned n  = b / 196u;
    const unsigned pc = b % 196u;
    const unsigned d2 = pc / 14u;
    const unsigned d3 = pc % 14u;

    const float* g    = in + (size_t)n * N_STRIDE;
    const float* cor1 = g;
    const float* cor2 = g + TSTRIDE;
    const float* cen1 = g + 2 * TSTRIDE;
    const float* cen2 = g + 3 * TSTRIDE;

    const unsigned tid = threadIdx.x;

    // ---- Prologue: one barrier total ----
    if (tid < 196u) {
        const unsigned ps = tid;
        const unsigned d4 = ps / 14u, d5 = ps % 14u;
        // center-side products
        const float e1 = cen1[ps] * cen1[(23u + d2) * 196u + ps] * cen1[(37u + d3) * 196u + ps];
        const float e2 = cen2[ps] * cen2[(23u + d2) * 196u + ps] * cen2[(37u + d3) * 196u + ps];
        // corner-side Lcx/Lcy gathers (14 distinct lines each, L1-resident)
        const float f1 = cor1[(23u + d4) * 196u + pc] * cor1[(37u + d5) * 196u + pc];
        const float f2 = cor2[(23u + d4) * 196u + pc] * cor2[(37u + d5) * 196u + pc];
        sM11[ps] = f1 * e1;
        sM21[ps] = f2 * e1;
        sM12[ps] = f1 * e2;
        sM22[ps] = f2 * e2;
    } else if (tid < 216u) {
        const unsigned q = tid - 196u;
        sK1[q] = 0.5f * cor1[pc] * cor1[(1u + q) * 196u + pc];
        sK2[q] = 0.5f * cor2[pc] * cor2[(1u + q) * 196u + pc];
    }
    __syncthreads();

    // ---- Main: thread owns one float4 chunk f (fixed), 4 q-values (q = qg + 5k) ----
    if (tid < 245u) {
        const unsigned qg = tid / 49u;           // 0..4
        const unsigned f  = tid - qg * 49u;      // 0..48
        const unsigned e  = 4u * f;

        const float4 m11 = *(const float4*)&sM11[e];
        const float4 m21 = *(const float4*)&sM21[e];
        const float4 m12 = *(const float4*)&sM12[e];
        const float4 m22 = *(const float4*)&sM22[e];

        size_t base = ((size_t)(n * 20u + qg) * 196u + pc) * 196u + e;
        const float* px1 = &cen1[(1u + qg) * 196u + e];
        const float* px2 = &cen2[(1u + qg) * 196u + e];

#pragma unroll
        for (unsigned k = 0; k < 4u; ++k) {
            const unsigned q = qg + 5u * k;
            const float4 x1 = *(const float4*)px1;
            const float4 x2 = *(const float4*)px2;
            const float k1 = sK1[q], k2 = sK2[q];

            float4* o1 = (float4*)(out + base);
            float4* o2 = (float4*)(out + (size_t)S_PER + base);
            float4* o3 = (float4*)(out + 2u * (size_t)S_PER + base);
            float4* o4 = (float4*)(out + 3u * (size_t)S_PER + base);

            *o1 = make_float4(k1 * m11.x * x1.x, k1 * m11.y * x1.y,
                              k1 * m11.z * x1.z, k1 * m11.w * x1.w);
            *o2 = make_float4(k2 * m21.x * x1.x, k2 * m21.y * x1.y,
                              k2 * m21.z * x1.z, k2 * m21.w * x1.w);
            *o3 = make_float4(k1 * m12.x * x2.x, k1 * m12.y * x2.y,
                              k1 * m12.z * x2.z, k1 * m12.w * x2.w);
            *o4 = make_float4(k2 * m22.x * x2.x, k2 * m22.y * x2.y,
                              k2 * m22.z * x2.z, k2 * m22.w * x2.w);

            base += (size_t)QSTEP;
            px1  += 5u * 196u;
            px2  += 5u * 196u;
        }
    }
}

extern "C" void kernel_launch(void* const* d_in, const int* in_sizes, int n_in,
                              void* d_out, int out_size, void* d_ws, size_t ws_size,
                              hipStream_t stream) {
    const float* in = (const float*)d_in[0];
    float* out = (float*)d_out;
    dim3 grid(32 * 196);           // one block per (n, d2, d3)
    dim3 block(256);
    plnet_kernel<<<grid, block, 0, stream>>>(in, out);
}

// Round 4
// 89.525 us; speedup vs baseline: 2.5577x; 1.1895x over previous
//
#include <hip/hip_runtime.h>

// out: 4 tensors (32, 20, 14, 14, 14, 14) fp32 concatenated.
// Block = (n, q, d2); each block writes 4 contiguous chunks of 14*196 floats.
//   out_p[d3][ps] = F_i[d3][ps] * G_j[d3][ps]
//   F_i[d3][ps]   = A_i[d3][d4] * B_i[d3][d5]          (corner side)
//   A_i[d3][d4]   = 0.5*cor_i[0,pc]*cor_i[1+q,pc]*cor_i[23+d4,pc],  pc=d2*14+d3
//   B_i[d3][d5]   = cor_i[37+d5,pc]
//   G_j[d3][ps]   = T_j[ps] * cen_j[37+d3,ps]          (center side)
//   T_j[ps]       = cen_j[0,ps]*cen_j[1+q,ps]*cen_j[23+d2,ps]
// p1=F1*G1  p2=F2*G1  p3=F1*G2  p4=F2*G2

#define S_PER 24586240u            // 32*20*14^4 elements per tensor
#define TSTRIDE (51 * 196)
#define N_STRIDE (204 * 196)

__global__ __launch_bounds__(256) void plnet_kernel(const float* __restrict__ in,
                                                    float* __restrict__ out) {
    __shared__ __align__(16) float sT1[196];
    __shared__ __align__(16) float sT2[196];
    __shared__ float sA1[196], sA2[196];   // [d3*14 + d4]
    __shared__ float sB1[196], sB2[196];   // [d3*14 + d5]

    const unsigned b  = blockIdx.x;        // = (n*20 + q)*14 + d2
    const unsigned d2 = b % 14u;
    const unsigned nq = b / 14u;
    const unsigned q  = nq % 20u;
    const unsigned n  = nq / 20u;

    const float* g    = in + (size_t)n * N_STRIDE;
    const float* cor1 = g;
    const float* cor2 = g + TSTRIDE;
    const float* cen1 = g + 2 * TSTRIDE;
    const float* cen2 = g + 3 * TSTRIDE;

    const unsigned tid = threadIdx.x;

    // ---- Prologue: build 6 small LDS tables, one barrier ----
    if (tid < 196u) {
        const unsigned ps = tid;
        // center side (coalesced row reads)
        sT1[ps] = cen1[ps] * cen1[(1u + q) * 196u + ps] * cen1[(23u + d2) * 196u + ps];
        sT2[ps] = cen2[ps] * cen2[(1u + q) * 196u + ps] * cen2[(23u + d2) * 196u + ps];
        // corner side (small gathers, L1/L2-hot)
        const unsigned d3 = ps / 14u;
        const unsigned k  = ps - d3 * 14u;
        const unsigned pc = d2 * 14u + d3;
        const float k1 = 0.5f * cor1[pc] * cor1[(1u + q) * 196u + pc];
        const float k2 = 0.5f * cor2[pc] * cor2[(1u + q) * 196u + pc];
        sA1[ps] = k1 * cor1[(23u + k) * 196u + pc];
        sA2[ps] = k2 * cor2[(23u + k) * 196u + pc];
        sB1[ps] = cor1[(37u + k) * 196u + pc];
        sB2[ps] = cor2[(37u + k) * 196u + pc];
    }
    __syncthreads();

    // ---- Main: 686 float4-items over (d3, ps/4); contiguous stores ----
    const size_t chunk = ((size_t)(n * 20u + q) * 196u + d2 * 14u) * 196u;
    float4* o1 = (float4*)(out + chunk);
    float4* o2 = (float4*)(out + (size_t)S_PER + chunk);
    float4* o3 = (float4*)(out + 2u * (size_t)S_PER + chunk);
    float4* o4 = (float4*)(out + 3u * (size_t)S_PER + chunk);

    for (unsigned c = tid; c < 686u; c += 256u) {
        const unsigned d3 = c / 49u;
        const unsigned f  = c - d3 * 49u;
        const unsigned e  = 4u * f;          // ps of first element

        const float4 t1 = *(const float4*)&sT1[e];
        const float4 t2 = *(const float4*)&sT2[e];
        const float4 v1 = *(const float4*)&cen1[(37u + d3) * 196u + e];
        const float4 v2 = *(const float4*)&cen2[(37u + d3) * 196u + e];

        const float4 G1 = make_float4(t1.x * v1.x, t1.y * v1.y, t1.z * v1.z, t1.w * v1.w);
        const float4 G2 = make_float4(t2.x * v2.x, t2.y * v2.y, t2.z * v2.z, t2.w * v2.w);

        // per-element corner factors
        unsigned d4 = e / 14u;
        unsigned d5 = e - d4 * 14u;
        float F1[4], F2[4];
#pragma unroll
        for (int l = 0; l < 4; ++l) {
            F1[l] = sA1[d3 * 14u + d4] * sB1[d3 * 14u + d5];
            F2[l] = sA2[d3 * 14u + d4] * sB2[d3 * 14u + d5];
            ++d5;
            const unsigned carry = (d5 == 14u);
            d4 += carry;
            d5 = carry ? 0u : d5;
        }

        o1[c] = make_float4(F1[0] * G1.x, F1[1] * G1.y, F1[2] * G1.z, F1[3] * G1.w);
        o2[c] = make_float4(F2[0] * G1.x, F2[1] * G1.y, F2[2] * G1.z, F2[3] * G1.w);
        o3[c] = make_float4(F1[0] * G2.x, F1[1] * G2.y, F1[2] * G2.z, F1[3] * G2.w);
        o4[c] = make_float4(F2[0] * G2.x, F2[1] * G2.y, F2[2] * G2.z, F2[3] * G2.w);
    }
}

extern "C" void kernel_launch(void* const* d_in, const int* in_sizes, int n_in,
                              void* d_out, int out_size, void* d_ws, size_t ws_size,
                              hipStream_t stream) {
    const float* in = (const float*)d_in[0];
    float* out = (float*)d_out;
    dim3 grid(32 * 20 * 14);       // one block per (n, q, d2)
    dim3 block(256);
    plnet_kernel<<<grid, block, 0, stream>>>(in, out);
}